// Round 3
// baseline (420.499 us; speedup 1.0000x reference)
//
#include <hip/hip_runtime.h>

#define NGRAPH 256
#define NNODE  512
#define KNN    6
#define NCAND  12
#define NF     64
#define SBF    72                 // bf16 row stride in shorts (144 B, 16B-aligned)
#define NT     768
#define NW     12                 // waves per block
// LDS layout (float indices):
#define PBF    18432              // hbf = 512*72 shorts = 73728 B at [0,PBF)
                                  // pbf = 512*72 shorts at [PBF, 36864)
#define CANDO  PBF                // cand: 512*12 ushort = 3072 floats (dead before convs)
#define SQO    (PBF + 3072)       // 512 floats (bf16 sq, then exact sq; dead before convs)
#define WTO    36864              // Wt bf16: 64*72 shorts = 2304 floats
#define LDS_FLOATS 39168
#define LDS_BYTES  (LDS_FLOATS*4) // 156672 B < 160 KiB
// pool/head scratch (pbf region, dead after last conv gather):
#define POOLP  PBF
#define POOLED (PBF + 512)
#define Y1OFF  (PBF + 576)
#define Y2OFF  (PBF + 832)
#define Y3OFF  (PBF + 1088)
#define BIG 1e30f

typedef float v4f __attribute__((ext_vector_type(4)));
typedef short v8s __attribute__((ext_vector_type(8)));

struct Params {
  const float *x;
  const float *W1,*b1,*a1, *W2,*b2,*a2;
  const float *Wc0,*bc0, *Wc1,*bc1, *Wc2,*bc2, *Wc3,*bc3;
  const float *W3,*b3,*a3, *W4,*b4,*a4;
  const float *Wh1,*bh1, *Wh2,*bh2, *Wh3,*bh3, *Wh4,*bh4;
  float *out;
};

// fp32 -> bf16 (RNE) as raw 16-bit
__device__ __forceinline__ unsigned f2bf(float x) {
  union { float f; unsigned u; } cc; cc.f = x;
  unsigned u = cc.u;
  return (u + 0x7FFFu + ((u >> 16) & 1u)) >> 16;
}
__device__ __forceinline__ float bflo(unsigned u) {
  union { unsigned u; float f; } c; c.u = u << 16; return c.f;
}
__device__ __forceinline__ float bfhi(unsigned u) {
  union { unsigned u; float f; } c; c.u = u & 0xffff0000u; return c.f;
}

__device__ __forceinline__ v8s bfrag(const unsigned short* base, int row, int c0) {
  return *(const v8s*)(base + row*SBF + c0);
}

// pack filter-e with its index in the low 9 mantissa bits (|perturb| << bf16 noise;
// candidate SET is all that matters — exact fp32 re-rank decides final order)
__device__ __forceinline__ float packe(float e, int j) {
  return __uint_as_float((__float_as_uint(e) & 0xFFFFFE00u) | (unsigned)j);
}

// sorted-ascending insert via min/max propagation (2 inst/stage)
__device__ __forceinline__ void ins8(float (&b)[8], float v) {
  if (v < b[7]) {
#pragma unroll
    for (int p = 0; p < 8; ++p) {
      float lo = fminf(b[p], v);
      v = fmaxf(b[p], v);
      b[p] = lo;
    }
  }
}
__device__ __forceinline__ void ins12(float (&b)[NCAND], float v) {
  if (v < b[NCAND-1]) {
#pragma unroll
    for (int p = 0; p < NCAND; ++p) {
      float lo = fminf(b[p], v);
      v = fmaxf(b[p], v);
      b[p] = lo;
    }
  }
}

// stage W^T as bf16 into Wt: Wt[col][k] = bf16(W[k*64+col]); tid<512 only
__device__ __forceinline__ void stage_wt(const float* W, unsigned short* wt, int tid) {
  const int col = tid >> 3, ks = (tid & 7) * 8;
  const float* wp = W + col;
  unsigned d[4];
#pragma unroll
  for (int i = 0; i < 4; ++i) {
    unsigned lo = f2bf(wp[(ks + 2*i    ) * NF]);
    unsigned hi = f2bf(wp[(ks + 2*i + 1) * NF]);
    d[i] = lo | (hi << 16);
  }
  *(uint4*)&wt[col*SBF + ks] = make_uint4(d[0], d[1], d[2], d[3]);
}

// occupancy is LDS-bound to 1 block/CU = 12 waves = 3 waves/SIMD; ask the
// compiler for exactly that so it can use ~168 VGPRs (84 before -> spilled
// xr16[16]/acc[64] to scratch: 122 MB/dispatch of HBM writes)
__global__ __launch_bounds__(NT, 3) void fused_gnn(Params P) {
  extern __shared__ float lds[];
  unsigned short* hbf  = (unsigned short*)lds;
  unsigned short* pbf  = (unsigned short*)&lds[PBF];
  unsigned short* wt   = (unsigned short*)&lds[WTO];
  unsigned short* cand = (unsigned short*)&lds[CANDO];
  const int tid  = threadIdx.x;
  const int g    = blockIdx.x;
  const int rA   = tid;                  // row ownership for tid<512
  const int lane = tid & 63;
  const int w    = tid >> 6;             // wave 0..11
  const int c    = lane & 15;
  const int qq   = lane >> 4;            // 0..3

  const float* xgp = P.x + (size_t)g * NNODE * NF;
  const float4* xg = (const float4*)xgp;

  // ---- stage x[g] as bf16 into hbf ----
#pragma unroll 1
  for (int i = tid; i < NNODE*NF/4; i += NT) {
    float4 v = xg[i];
    int row = i >> 4, k4 = i & 15;
    unsigned lo = f2bf(v.x) | (f2bf(v.y) << 16);
    unsigned hi = f2bf(v.z) | (f2bf(v.w) << 16);
    *(uint2*)&hbf[row*SBF + 4*k4] = make_uint2(lo, hi);
  }
  __syncthreads();

  // ---- filter sq from bf16 values (b128 row reads: 2-way conflict, was 8-way b32) ----
  if (tid < 512) {
    const uint4* xr = (const uint4*)(hbf + rA*SBF);
    float s = 0.f;
#pragma unroll
    for (int k = 0; k < 8; ++k) {
      uint4 u = xr[k];
      float f;
      f = bflo(u.x); s = fmaf(f, f, s); f = bfhi(u.x); s = fmaf(f, f, s);
      f = bflo(u.y); s = fmaf(f, f, s); f = bfhi(u.y); s = fmaf(f, f, s);
      f = bflo(u.z); s = fmaf(f, f, s); f = bfhi(u.z); s = fmaf(f, f, s);
      f = bflo(u.w); s = fmaf(f, f, s); f = bfhi(u.w); s = fmaf(f, f, s);
    }
    lds[SQO + rA] = s;
  }
  __syncthreads();

  // ==== kNN filter: bf16 MFMA Gram (swapped operands -> no LDS transpose)
  //      + packed lane-local top-8 ====
  // mfma(B_jrows, A_irows): D'[m][n] = <x[j0+m], x[i0+n]>, so lane (qq,c)
  // reg r holds <x[i0+c], x[j0+qq*4+r]> directly — the old tb round-trip
  // (4 b32 writes + b128 read + lgkm stall per jt) is deleted.
  {
#pragma unroll 1
    for (int tt = w; tt < 32; tt += NW) {
      const int i0 = tt * 16;
      v8s A0 = bfrag(hbf, i0 + c, qq*8);
      v8s A1 = bfrag(hbf, i0 + c, 32 + qq*8);
      const int myrow = i0 + c;

      float d8[8];
#pragma unroll
      for (int m = 0; m < 8; ++m) d8[m] = BIG;

#pragma unroll 1
      for (int jt = 0; jt < 32; ++jt) {
        const int j0 = jt * 16;
        v8s B0 = bfrag(hbf, j0 + c, qq*8);
        v8s B1 = bfrag(hbf, j0 + c, 32 + qq*8);
        v4f acc = {0.f, 0.f, 0.f, 0.f};
        acc = __builtin_amdgcn_mfma_f32_16x16x32_bf16(B0, A0, acc, 0, 0, 0);
        acc = __builtin_amdgcn_mfma_f32_16x16x32_bf16(B1, A1, acc, 0, 0, 0);
        float4 sv = *(const float4*)&lds[SQO + j0 + qq*4];
        float e0 = fmaf(-2.f, acc[0], sv.x);
        float e1 = fmaf(-2.f, acc[1], sv.y);
        float e2 = fmaf(-2.f, acc[2], sv.z);
        float e3 = fmaf(-2.f, acc[3], sv.w);
        const int jb = j0 + qq*4;
        if (jb     == myrow) e0 = BIG;
        if (jb + 1 == myrow) e1 = BIG;
        if (jb + 2 == myrow) e2 = BIG;
        if (jb + 3 == myrow) e3 = BIG;
        ins8(d8, packe(e0, jb));
        ins8(d8, packe(e1, jb+1));
        ins8(d8, packe(e2, jb+2));
        ins8(d8, packe(e3, jb+3));
      }

      // merge the 4 qq-lanes sharing this row: 2 butterfly stages, capacity 12
      float cd[NCAND];
#pragma unroll
      for (int m = 0; m < 8; ++m) cd[m] = d8[m];
#pragma unroll
      for (int m = 8; m < NCAND; ++m) cd[m] = BIG;
      {
        float pd[8];
#pragma unroll
        for (int s = 0; s < 8; ++s) pd[s] = __shfl_xor(cd[s], 16);
#pragma unroll
        for (int s = 0; s < 8; ++s) ins12(cd, pd[s]);
      }
      {
        float pd[NCAND];
#pragma unroll
        for (int s = 0; s < NCAND; ++s) pd[s] = __shfl_xor(cd[s], 32);
#pragma unroll
        for (int s = 0; s < NCAND; ++s) ins12(cd, pd[s]);
      }
      if (lane < 16) {
#pragma unroll
        for (int s = 0; s < NCAND; ++s)
          cand[(i0 + lane)*NCAND + s] =
            (unsigned short)(__float_as_uint(cd[s]) & 0x1FFu);
      }
    }
  }
  __syncthreads();   // filter done; SQO safe to overwrite

  // ==== exact fp32 refine from GLOBAL x — final indices exact ====
  float4 xr16[16];
  if (tid < 512) {
    const float4* xrow = (const float4*)(xgp + rA*NF);
#pragma unroll
    for (int k4 = 0; k4 < 16; ++k4) xr16[k4] = xrow[k4];
    float s0 = 0.f;
#pragma unroll
    for (int k4 = 0; k4 < 16; ++k4) {
      float4 a = xr16[k4];
      s0 = fmaf(a.x,a.x,s0); s0 = fmaf(a.y,a.y,s0); s0 = fmaf(a.z,a.z,s0); s0 = fmaf(a.w,a.w,s0);
    }
    lds[SQO + rA] = s0;
  }
  __syncthreads();   // exact sq published

  int nbrA[KNN];
  if (tid < 512) {
    float nd[6]; int ni[6];
#pragma unroll
    for (int m = 0; m < 6; ++m) { nd[m] = BIG; ni[m] = 0x7fffffff; }
    int cnd[NCAND];
#pragma unroll
    for (int s = 0; s < NCAND; ++s) cnd[s] = cand[rA*NCAND + s];

#pragma unroll 1
    for (int s = 0; s < NCAND; ++s) {
      int j = cnd[s];
      const float4* xj = (const float4*)(xgp + j*NF);
      float4 aa = {0.f, 0.f, 0.f, 0.f};
#pragma unroll
      for (int k4 = 0; k4 < 16; ++k4) {
        float4 v = xj[k4];
        aa.x = fmaf(xr16[k4].x, v.x, aa.x); aa.y = fmaf(xr16[k4].y, v.y, aa.y);
        aa.z = fmaf(xr16[k4].z, v.z, aa.z); aa.w = fmaf(xr16[k4].w, v.w, aa.w);
      }
      float e = fmaf(-2.f, (aa.x+aa.y)+(aa.z+aa.w), lds[SQO + j]);
      if (e < nd[5] || (e == nd[5] && j < ni[5])) {
#pragma unroll
        for (int pp = 0; pp < 6; ++pp) {
          bool lt = (e < nd[pp]) || (e == nd[pp] && j < ni[pp]);
          float tb2 = nd[pp]; int ti = ni[pp];
          nd[pp] = lt ? e : tb2;  ni[pp] = lt ? j : ti;
          e      = lt ? tb2 : e;  j      = lt ? ti : j;
        }
      }
    }
#pragma unroll
    for (int m = 0; m < 6; ++m) nbrA[m] = ni[m];
  }

  // ==== layers: bf16 MFMA GEMMs over 12 waves ====
  const float* Ws[8]  = {P.W1, P.W2, P.Wc0, P.Wc1, P.Wc2, P.Wc3, P.W3, P.W4};
  const float* bs[8]  = {P.b1, P.b2, P.bc0, P.bc1, P.bc2, P.bc3, P.b3, P.b4};
  const float* as[8]  = {P.a1, P.a2, 0,     0,     0,     0,     P.a3, P.a4};

#pragma unroll 1
  for (int L = 0; L < 8; ++L) {
    const bool isconv = (L >= 2 && L <= 5);
    __syncthreads();                   // prior h stable / prior Wt reads done / cand dead
    if (tid < 512) stage_wt(Ws[L], wt, tid);
    __syncthreads();                   // Wt ready

    v8s B0[4], B1[4];
#pragma unroll
    for (int n = 0; n < 4; ++n) {
      B0[n] = bfrag(wt, n*16 + c, qq*8);
      B1[n] = bfrag(wt, n*16 + c, 32 + qq*8);
    }
    float br[4], ar[4];
    if (!isconv) {
#pragma unroll
      for (int n = 0; n < 4; ++n) { br[n] = bs[L][n*16 + c]; ar[n] = as[L][n*16 + c]; }
    }

#pragma unroll 1
    for (int tt = w; tt < 32; tt += NW) {
      const int i0 = tt * 16;
      v8s A0 = bfrag(hbf, i0 + c, qq*8);
      v8s A1 = bfrag(hbf, i0 + c, 32 + qq*8);
#pragma unroll
      for (int n = 0; n < 4; ++n) {
        v4f acc = {0.f, 0.f, 0.f, 0.f};
        acc = __builtin_amdgcn_mfma_f32_16x16x32_bf16(A0, B0[n], acc, 0, 0, 0);
        acc = __builtin_amdgcn_mfma_f32_16x16x32_bf16(A1, B1[n], acc, 0, 0, 0);
        if (isconv) {
#pragma unroll
          for (int r = 0; r < 4; ++r)
            pbf[(i0 + qq*4 + r)*SBF + n*16 + c] = (unsigned short)f2bf(acc[r]);
        } else {
#pragma unroll
          for (int r = 0; r < 4; ++r) {
            float v = acc[r] + br[n];
            v = v >= 0.f ? v : ar[n]*v;
            hbf[(i0 + qq*4 + r)*SBF + n*16 + c] = (unsigned short)f2bf(v);
          }
        }
      }
    }

    if (isconv) {
      __syncthreads();                 // all p published; all h A-reads done
      if (tid < 512) {
        // gather: h_i + 6b + sum of 6 neighbor p-rows (fp32 accumulate, 64 feats)
        // b128 row reads: 4x fewer LDS instrs, 2-way (free) vs 8-way b32 conflicts
        float acc[NF];
        const uint4* hr = (const uint4*)&hbf[rA*SBF];
#pragma unroll
        for (int kk = 0; kk < 8; ++kk) {
          uint4 u = hr[kk];
          acc[8*kk+0] = bflo(u.x); acc[8*kk+1] = bfhi(u.x);
          acc[8*kk+2] = bflo(u.y); acc[8*kk+3] = bfhi(u.y);
          acc[8*kk+4] = bflo(u.z); acc[8*kk+5] = bfhi(u.z);
          acc[8*kk+6] = bflo(u.w); acc[8*kk+7] = bfhi(u.w);
        }
        {
          const float4* bp = (const float4*)bs[L];
#pragma unroll
          for (int o4 = 0; o4 < 16; ++o4) {
            float4 bv = bp[o4];
            acc[4*o4]   = fmaf(6.f, bv.x, acc[4*o4]);
            acc[4*o4+1] = fmaf(6.f, bv.y, acc[4*o4+1]);
            acc[4*o4+2] = fmaf(6.f, bv.z, acc[4*o4+2]);
            acc[4*o4+3] = fmaf(6.f, bv.w, acc[4*o4+3]);
          }
        }
#pragma unroll
        for (int mm = 0; mm < KNN; ++mm) {
          const uint4* pr = (const uint4*)&pbf[nbrA[mm]*SBF];
#pragma unroll
          for (int kk = 0; kk < 8; ++kk) {
            uint4 u = pr[kk];
            acc[8*kk+0] += bflo(u.x); acc[8*kk+1] += bfhi(u.x);
            acc[8*kk+2] += bflo(u.y); acc[8*kk+3] += bfhi(u.y);
            acc[8*kk+4] += bflo(u.z); acc[8*kk+5] += bfhi(u.z);
            acc[8*kk+6] += bflo(u.w); acc[8*kk+7] += bfhi(u.w);
          }
        }
        uint4* hw = (uint4*)&hbf[rA*SBF];
#pragma unroll
        for (int kk = 0; kk < 8; ++kk) {
          uint4 o;
          o.x = f2bf(acc[8*kk+0]) | (f2bf(acc[8*kk+1]) << 16);
          o.y = f2bf(acc[8*kk+2]) | (f2bf(acc[8*kk+3]) << 16);
          o.z = f2bf(acc[8*kk+4]) | (f2bf(acc[8*kk+5]) << 16);
          o.w = f2bf(acc[8*kk+6]) | (f2bf(acc[8*kk+7]) << 16);
          hw[kk] = o;
        }
      }
      // own-row write only; next layer's A-reads guarded by loop-top barrier
    }
  }
  __syncthreads();   // h final

  // ---- global add pool: 8 chunks of 64 rows (tid<512) ----
  if (tid < 512) {
    int f = tid & 63, cch = tid >> 6;      // cch 0..7
    int rstart = cch * 64;
    float s = 0.f;
#pragma unroll 1
    for (int r = 0; r < 64; ++r) {
      unsigned u = hbf[(rstart + r)*SBF + f];
      union { unsigned u; float ff; } cv; cv.u = u << 16;
      s += cv.ff;
    }
    lds[POOLP + cch*64 + f] = s;
  }
  __syncthreads();
  if (tid < 64) {
    float pool = 0.f;
#pragma unroll
    for (int cc = 0; cc < 8; ++cc) pool += lds[POOLP + cc*64 + tid];
    lds[POOLED + tid] = pool;
  }
  __syncthreads();

  // ---- head MLP (fp32) ----
  if (tid < 256) {
    float acc = P.bh1[tid];
#pragma unroll 4
    for (int k = 0; k < 64; ++k) acc = fmaf(lds[POOLED+k], P.Wh1[k*256 + tid], acc);
    lds[Y1OFF + tid] = acc >= 0.f ? acc : 0.2f*acc;
  }
  __syncthreads();
  if (tid < 256) {
    float acc = P.bh2[tid];
#pragma unroll 4
    for (int k = 0; k < 256; ++k) acc = fmaf(lds[Y1OFF+k], P.Wh2[k*256 + tid], acc);
    lds[Y2OFF + tid] = acc >= 0.f ? acc : 0.2f*acc;
  }
  __syncthreads();
  if (tid < 64) {
    float acc = P.bh3[tid];
#pragma unroll 4
    for (int k = 0; k < 256; ++k) acc = fmaf(lds[Y2OFF+k], P.Wh3[k*64 + tid], acc);
    lds[Y3OFF + tid] = acc >= 0.f ? acc : 0.2f*acc;
  }
  __syncthreads();
  if (tid == 0) {
    float acc = P.bh4[0];
#pragma unroll 4
    for (int k = 0; k < 64; ++k) acc = fmaf(lds[Y3OFF+k], P.Wh4[k], acc);
    P.out[g] = acc;
  }
}

extern "C" void kernel_launch(void* const* d_in, const int* in_sizes, int n_in,
                              void* d_out, int out_size, void* d_ws, size_t ws_size,
                              hipStream_t stream) {
  Params P;
  P.x   = (const float*)d_in[0];
  P.W1  = (const float*)d_in[1];  P.b1  = (const float*)d_in[2];  P.a1 = (const float*)d_in[3];
  P.W2  = (const float*)d_in[4];  P.b2  = (const float*)d_in[5];  P.a2 = (const float*)d_in[6];
  P.Wc0 = (const float*)d_in[7];  P.bc0 = (const float*)d_in[8];
  P.Wc1 = (const float*)d_in[9];  P.bc1 = (const float*)d_in[10];
  P.Wc2 = (const float*)d_in[11]; P.bc2 = (const float*)d_in[12];
  P.Wc3 = (const float*)d_in[13]; P.bc3 = (const float*)d_in[14];
  P.W3  = (const float*)d_in[15]; P.b3  = (const float*)d_in[16]; P.a3 = (const float*)d_in[17];
  P.W4  = (const float*)d_in[18]; P.b4  = (const float*)d_in[19]; P.a4 = (const float*)d_in[20];
  P.Wh1 = (const float*)d_in[21]; P.bh1 = (const float*)d_in[22];
  P.Wh2 = (const float*)d_in[23]; P.bh2 = (const float*)d_in[24];
  P.Wh3 = (const float*)d_in[25]; P.bh3 = (const float*)d_in[26];
  P.Wh4 = (const float*)d_in[27]; P.bh4 = (const float*)d_in[28];
  P.out = (float*)d_out;

  (void)hipFuncSetAttribute(reinterpret_cast<const void*>(fused_gnn),
                            hipFuncAttributeMaxDynamicSharedMemorySize, LDS_BYTES);

  fused_gnn<<<NGRAPH, NT, LDS_BYTES, stream>>>(P);
}

// Round 4
// 329.810 us; speedup vs baseline: 1.2750x; 1.2750x over previous
//
#include <hip/hip_runtime.h>

#define NGRAPH 256
#define NNODE  512
#define KNN    6
#define NCAND  12
#define NF     64
#define SBF    72                 // bf16 row stride in shorts (144 B, 16B-aligned)
#define NT     768
#define NW     12                 // waves per block
// LDS layout (float indices):
#define PBF    18432              // hbf = 512*72 shorts = 73728 B at [0,PBF)
                                  // pbf = 512*72 shorts at [PBF, 36864)
#define CANDO  PBF                // cand: 512*12 ushort = 3072 floats (dead before convs)
#define SQO    (PBF + 3072)       // 512 floats (bf16 sq, then exact sq; dead before convs)
#define WTO    36864              // Wt bf16: 64*72 shorts = 2304 floats
#define LDS_FLOATS 39168
#define LDS_BYTES  (LDS_FLOATS*4) // 156672 B < 160 KiB
// pool/head scratch (pbf region, dead after last conv gather):
#define POOLP  PBF
#define POOLED (PBF + 512)
#define Y1OFF  (PBF + 576)
#define Y2OFF  (PBF + 832)
#define Y3OFF  (PBF + 1088)
#define BIG 1e30f

typedef float v4f __attribute__((ext_vector_type(4)));
typedef short v8s __attribute__((ext_vector_type(8)));

struct Params {
  const float *x;
  const float *W1,*b1,*a1, *W2,*b2,*a2;
  const float *Wc0,*bc0, *Wc1,*bc1, *Wc2,*bc2, *Wc3,*bc3;
  const float *W3,*b3,*a3, *W4,*b4,*a4;
  const float *Wh1,*bh1, *Wh2,*bh2, *Wh3,*bh3, *Wh4,*bh4;
  float *out;
};

// fp32 -> bf16 (RNE) as raw 16-bit
__device__ __forceinline__ unsigned f2bf(float x) {
  union { float f; unsigned u; } cc; cc.f = x;
  unsigned u = cc.u;
  return (u + 0x7FFFu + ((u >> 16) & 1u)) >> 16;
}
__device__ __forceinline__ float bflo(unsigned u) {
  union { unsigned u; float f; } c; c.u = u << 16; return c.f;
}
__device__ __forceinline__ float bfhi(unsigned u) {
  union { unsigned u; float f; } c; c.u = u & 0xffff0000u; return c.f;
}

__device__ __forceinline__ v8s bfrag(const unsigned short* base, int row, int c0) {
  return *(const v8s*)(base + row*SBF + c0);
}

// pack filter-e with its index in the low 9 mantissa bits (|perturb| << bf16 noise;
// candidate SET is all that matters — exact fp32 re-rank decides final order)
__device__ __forceinline__ float packe(float e, int j) {
  return __uint_as_float((__float_as_uint(e) & 0xFFFFFE00u) | (unsigned)j);
}

// sorted-ascending insert via min/max propagation (2 inst/stage)
__device__ __forceinline__ void ins8(float (&b)[8], float v) {
  if (v < b[7]) {
#pragma unroll
    for (int p = 0; p < 8; ++p) {
      float lo = fminf(b[p], v);
      v = fmaxf(b[p], v);
      b[p] = lo;
    }
  }
}
__device__ __forceinline__ void ins12(float (&b)[NCAND], float v) {
  if (v < b[NCAND-1]) {
#pragma unroll
    for (int p = 0; p < NCAND; ++p) {
      float lo = fminf(b[p], v);
      v = fmaxf(b[p], v);
      b[p] = lo;
    }
  }
}

// unpack 16 bf16 (2x uint4) -> set / add into a16
__device__ __forceinline__ void set16(float (&a)[16], uint4 u0, uint4 u1) {
  a[0]=bflo(u0.x); a[1]=bfhi(u0.x); a[2]=bflo(u0.y); a[3]=bfhi(u0.y);
  a[4]=bflo(u0.z); a[5]=bfhi(u0.z); a[6]=bflo(u0.w); a[7]=bfhi(u0.w);
  a[8]=bflo(u1.x); a[9]=bfhi(u1.x); a[10]=bflo(u1.y); a[11]=bfhi(u1.y);
  a[12]=bflo(u1.z); a[13]=bfhi(u1.z); a[14]=bflo(u1.w); a[15]=bfhi(u1.w);
}
__device__ __forceinline__ void add16(float (&a)[16], uint4 u0, uint4 u1) {
  a[0]+=bflo(u0.x); a[1]+=bfhi(u0.x); a[2]+=bflo(u0.y); a[3]+=bfhi(u0.y);
  a[4]+=bflo(u0.z); a[5]+=bfhi(u0.z); a[6]+=bflo(u0.w); a[7]+=bfhi(u0.w);
  a[8]+=bflo(u1.x); a[9]+=bfhi(u1.x); a[10]+=bflo(u1.y); a[11]+=bfhi(u1.y);
  a[12]+=bflo(u1.z); a[13]+=bfhi(u1.z); a[14]+=bflo(u1.w); a[15]+=bfhi(u1.w);
}

// stage W^T as bf16 into Wt: Wt[col][k] = bf16(W[k*64+col]); tid<512 only
__device__ __forceinline__ void stage_wt(const float* W, unsigned short* wt, int tid) {
  const int col = tid >> 3, ks = (tid & 7) * 8;
  const float* wp = W + col;
  unsigned d[4];
#pragma unroll
  for (int i = 0; i < 4; ++i) {
    unsigned lo = f2bf(wp[(ks + 2*i    ) * NF]);
    unsigned hi = f2bf(wp[(ks + 2*i + 1) * NF]);
    d[i] = lo | (hi << 16);
  }
  *(uint4*)&wt[col*SBF + ks] = make_uint4(d[0], d[1], d[2], d[3]);
}

// NOTE: compiler pins 84 VGPRs (6 waves/EU heuristic) regardless of
// __launch_bounds__ min-waves — so every per-thread live set below is
// structurally kept under ~60 regs (chunked gather, streamed refine,
// no runtime-indexed arrays). No scratch.
__global__ __launch_bounds__(NT) void fused_gnn(Params P) {
  extern __shared__ float lds[];
  unsigned short* hbf  = (unsigned short*)lds;
  unsigned short* pbf  = (unsigned short*)&lds[PBF];
  unsigned short* wt   = (unsigned short*)&lds[WTO];
  unsigned short* cand = (unsigned short*)&lds[CANDO];
  const int tid  = threadIdx.x;
  const int g    = blockIdx.x;
  const int rA   = tid;                  // row ownership for tid<512
  const int lane = tid & 63;
  const int w    = tid >> 6;             // wave 0..11
  const int c    = lane & 15;
  const int qq   = lane >> 4;            // 0..3

  const float* xgp = P.x + (size_t)g * NNODE * NF;
  const float4* xg = (const float4*)xgp;

  // ---- stage x[g] as bf16 into hbf ----
#pragma unroll 1
  for (int i = tid; i < NNODE*NF/4; i += NT) {
    float4 v = xg[i];
    int row = i >> 4, k4 = i & 15;
    unsigned lo = f2bf(v.x) | (f2bf(v.y) << 16);
    unsigned hi = f2bf(v.z) | (f2bf(v.w) << 16);
    *(uint2*)&hbf[row*SBF + 4*k4] = make_uint2(lo, hi);
  }
  __syncthreads();

  // ---- filter sq from bf16 values (b128 row reads) ----
  if (tid < 512) {
    const uint4* xr = (const uint4*)(hbf + rA*SBF);
    float s = 0.f;
#pragma unroll
    for (int k = 0; k < 8; ++k) {
      uint4 u = xr[k];
      float f;
      f = bflo(u.x); s = fmaf(f, f, s); f = bfhi(u.x); s = fmaf(f, f, s);
      f = bflo(u.y); s = fmaf(f, f, s); f = bfhi(u.y); s = fmaf(f, f, s);
      f = bflo(u.z); s = fmaf(f, f, s); f = bfhi(u.z); s = fmaf(f, f, s);
      f = bflo(u.w); s = fmaf(f, f, s); f = bfhi(u.w); s = fmaf(f, f, s);
    }
    lds[SQO + rA] = s;
  }
  __syncthreads();

  // ==== kNN filter: bf16 MFMA Gram (swapped operands -> no LDS transpose)
  //      + packed lane-local top-8 ====
  // mfma(B_jrows, A_irows): lane (qq,c) reg r holds <x[i0+c], x[j0+qq*4+r]>.
  {
#pragma unroll 1
    for (int tt = w; tt < 32; tt += NW) {
      const int i0 = tt * 16;
      v8s A0 = bfrag(hbf, i0 + c, qq*8);
      v8s A1 = bfrag(hbf, i0 + c, 32 + qq*8);
      const int myrow = i0 + c;

      float d8[8];
#pragma unroll
      for (int m = 0; m < 8; ++m) d8[m] = BIG;

#pragma unroll 1
      for (int jt = 0; jt < 32; ++jt) {
        const int j0 = jt * 16;
        v8s B0 = bfrag(hbf, j0 + c, qq*8);
        v8s B1 = bfrag(hbf, j0 + c, 32 + qq*8);
        v4f acc = {0.f, 0.f, 0.f, 0.f};
        acc = __builtin_amdgcn_mfma_f32_16x16x32_bf16(B0, A0, acc, 0, 0, 0);
        acc = __builtin_amdgcn_mfma_f32_16x16x32_bf16(B1, A1, acc, 0, 0, 0);
        float4 sv = *(const float4*)&lds[SQO + j0 + qq*4];
        float e0 = fmaf(-2.f, acc[0], sv.x);
        float e1 = fmaf(-2.f, acc[1], sv.y);
        float e2 = fmaf(-2.f, acc[2], sv.z);
        float e3 = fmaf(-2.f, acc[3], sv.w);
        const int jb = j0 + qq*4;
        if (jb     == myrow) e0 = BIG;
        if (jb + 1 == myrow) e1 = BIG;
        if (jb + 2 == myrow) e2 = BIG;
        if (jb + 3 == myrow) e3 = BIG;
        ins8(d8, packe(e0, jb));
        ins8(d8, packe(e1, jb+1));
        ins8(d8, packe(e2, jb+2));
        ins8(d8, packe(e3, jb+3));
      }

      // merge the 4 qq-lanes sharing this row: 2 butterfly stages, capacity 12
      float cd[NCAND];
#pragma unroll
      for (int m = 0; m < 8; ++m) cd[m] = d8[m];
#pragma unroll
      for (int m = 8; m < NCAND; ++m) cd[m] = BIG;
      {
        float pd[8];
#pragma unroll
        for (int s = 0; s < 8; ++s) pd[s] = __shfl_xor(cd[s], 16);
#pragma unroll
        for (int s = 0; s < 8; ++s) ins12(cd, pd[s]);
      }
      {
        float pd[NCAND];
#pragma unroll
        for (int s = 0; s < NCAND; ++s) pd[s] = __shfl_xor(cd[s], 32);
#pragma unroll
        for (int s = 0; s < NCAND; ++s) ins12(cd, pd[s]);
      }
      if (lane < 16) {
#pragma unroll
        for (int s = 0; s < NCAND; ++s)
          cand[(i0 + lane)*NCAND + s] =
            (unsigned short)(__float_as_uint(cd[s]) & 0x1FFu);
      }
    }
  }
  __syncthreads();   // filter done; SQO safe to overwrite

  // ==== exact fp32 refine from GLOBAL x — streamed, no resident row array ====
  if (tid < 512) {
    const float4* xrow = (const float4*)(xgp + rA*NF);
    float s0 = 0.f;
#pragma unroll
    for (int k4 = 0; k4 < 16; ++k4) {
      float4 a = xrow[k4];
      s0 = fmaf(a.x,a.x,s0); s0 = fmaf(a.y,a.y,s0); s0 = fmaf(a.z,a.z,s0); s0 = fmaf(a.w,a.w,s0);
    }
    lds[SQO + rA] = s0;
  }
  __syncthreads();   // exact sq published

  int nbrA[KNN];
  if (tid < 512) {
    const float4* xrow = (const float4*)(xgp + rA*NF);   // L1/L2-hot re-reads
    float nd[6]; int ni[6];
#pragma unroll
    for (int m = 0; m < 6; ++m) { nd[m] = BIG; ni[m] = 0x7fffffff; }
    int cnd[NCAND];
#pragma unroll
    for (int s = 0; s < NCAND; ++s) cnd[s] = cand[rA*NCAND + s];

#pragma unroll 1
    for (int s = 0; s < NCAND; ++s) {
      int j = cnd[s];
      const float4* xj = (const float4*)(xgp + j*NF);
      float4 aa = {0.f, 0.f, 0.f, 0.f};
#pragma unroll
      for (int k4 = 0; k4 < 16; ++k4) {
        float4 a = xrow[k4];
        float4 v = xj[k4];
        aa.x = fmaf(a.x, v.x, aa.x); aa.y = fmaf(a.y, v.y, aa.y);
        aa.z = fmaf(a.z, v.z, aa.z); aa.w = fmaf(a.w, v.w, aa.w);
      }
      float e = fmaf(-2.f, (aa.x+aa.y)+(aa.z+aa.w), lds[SQO + j]);
      if (e < nd[5] || (e == nd[5] && j < ni[5])) {
#pragma unroll
        for (int pp = 0; pp < 6; ++pp) {
          bool lt = (e < nd[pp]) || (e == nd[pp] && j < ni[pp]);
          float tb2 = nd[pp]; int ti = ni[pp];
          nd[pp] = lt ? e : tb2;  ni[pp] = lt ? j : ti;
          e      = lt ? tb2 : e;  j      = lt ? ti : j;
        }
      }
    }
#pragma unroll
    for (int m = 0; m < 6; ++m) nbrA[m] = ni[m];
  }

  // ==== layers: bf16 MFMA GEMMs over 12 waves ====
  // pointer select via uniform ternary chain (SGPR cselect) — NO stack arrays
#pragma unroll 1
  for (int L = 0; L < 8; ++L) {
    const bool isconv = (L >= 2 && L <= 5);
    const float* Wl = L==0?P.W1 : L==1?P.W2 : L==2?P.Wc0 : L==3?P.Wc1 :
                      L==4?P.Wc2 : L==5?P.Wc3 : L==6?P.W3 : P.W4;
    const float* bl = L==0?P.b1 : L==1?P.b2 : L==2?P.bc0 : L==3?P.bc1 :
                      L==4?P.bc2 : L==5?P.bc3 : L==6?P.b3 : P.b4;
    const float* al = L==0?P.a1 : L==1?P.a2 : L==6?P.a3 : P.a4;  // only read when !isconv

    __syncthreads();                   // prior h stable / prior Wt reads done / cand dead
    if (tid < 512) stage_wt(Wl, wt, tid);
    __syncthreads();                   // Wt ready

    v8s B0[4], B1[4];
#pragma unroll
    for (int n = 0; n < 4; ++n) {
      B0[n] = bfrag(wt, n*16 + c, qq*8);
      B1[n] = bfrag(wt, n*16 + c, 32 + qq*8);
    }
    float br[4], ar[4];
    if (!isconv) {
#pragma unroll
      for (int n = 0; n < 4; ++n) { br[n] = bl[n*16 + c]; ar[n] = al[n*16 + c]; }
    }

#pragma unroll 1
    for (int tt = w; tt < 32; tt += NW) {
      const int i0 = tt * 16;
      v8s A0 = bfrag(hbf, i0 + c, qq*8);
      v8s A1 = bfrag(hbf, i0 + c, 32 + qq*8);
#pragma unroll
      for (int n = 0; n < 4; ++n) {
        v4f acc = {0.f, 0.f, 0.f, 0.f};
        acc = __builtin_amdgcn_mfma_f32_16x16x32_bf16(A0, B0[n], acc, 0, 0, 0);
        acc = __builtin_amdgcn_mfma_f32_16x16x32_bf16(A1, B1[n], acc, 0, 0, 0);
        if (isconv) {
#pragma unroll
          for (int r = 0; r < 4; ++r)
            pbf[(i0 + qq*4 + r)*SBF + n*16 + c] = (unsigned short)f2bf(acc[r]);
        } else {
#pragma unroll
          for (int r = 0; r < 4; ++r) {
            float v = acc[r] + br[n];
            v = v >= 0.f ? v : ar[n]*v;
            hbf[(i0 + qq*4 + r)*SBF + n*16 + c] = (unsigned short)f2bf(v);
          }
        }
      }
    }

    if (isconv) {
      __syncthreads();                 // all p published; all h A-reads done
      if (tid < 512) {
        // gather: h_i + 6b + sum of 6 neighbor p-rows, CHUNKED 4x16 feats so
        // live set stays ~40 VGPRs (acc[64] spilled to scratch before:
        // 122-238 MB/dispatch of HBM round-trip). unroll 1 = keep chunks apart.
        const float4* bp = (const float4*)bl;
#pragma unroll 1
        for (int ch = 0; ch < 4; ++ch) {
          float a16[16];
          const int co = ch*16;      // short offset of this chunk
          {
            const uint4* hr = (const uint4*)&hbf[rA*SBF + co];
            set16(a16, hr[0], hr[1]);
          }
          {
            float4 b0 = bp[ch*4+0], b1 = bp[ch*4+1], b2 = bp[ch*4+2], b3 = bp[ch*4+3];
            a16[0]  = fmaf(6.f, b0.x, a16[0]);  a16[1]  = fmaf(6.f, b0.y, a16[1]);
            a16[2]  = fmaf(6.f, b0.z, a16[2]);  a16[3]  = fmaf(6.f, b0.w, a16[3]);
            a16[4]  = fmaf(6.f, b1.x, a16[4]);  a16[5]  = fmaf(6.f, b1.y, a16[5]);
            a16[6]  = fmaf(6.f, b1.z, a16[6]);  a16[7]  = fmaf(6.f, b1.w, a16[7]);
            a16[8]  = fmaf(6.f, b2.x, a16[8]);  a16[9]  = fmaf(6.f, b2.y, a16[9]);
            a16[10] = fmaf(6.f, b2.z, a16[10]); a16[11] = fmaf(6.f, b2.w, a16[11]);
            a16[12] = fmaf(6.f, b3.x, a16[12]); a16[13] = fmaf(6.f, b3.y, a16[13]);
            a16[14] = fmaf(6.f, b3.z, a16[14]); a16[15] = fmaf(6.f, b3.w, a16[15]);
          }
#pragma unroll
          for (int mm = 0; mm < KNN; ++mm) {
            const uint4* pr = (const uint4*)&pbf[nbrA[mm]*SBF + co];
            add16(a16, pr[0], pr[1]);
          }
          uint4 o0, o1;
          o0.x = f2bf(a16[0])  | (f2bf(a16[1])  << 16);
          o0.y = f2bf(a16[2])  | (f2bf(a16[3])  << 16);
          o0.z = f2bf(a16[4])  | (f2bf(a16[5])  << 16);
          o0.w = f2bf(a16[6])  | (f2bf(a16[7])  << 16);
          o1.x = f2bf(a16[8])  | (f2bf(a16[9])  << 16);
          o1.y = f2bf(a16[10]) | (f2bf(a16[11]) << 16);
          o1.z = f2bf(a16[12]) | (f2bf(a16[13]) << 16);
          o1.w = f2bf(a16[14]) | (f2bf(a16[15]) << 16);
          uint4* hw = (uint4*)&hbf[rA*SBF + co];
          hw[0] = o0; hw[1] = o1;
        }
      }
      // own-row write only; next layer's A-reads guarded by loop-top barrier
    }
  }
  __syncthreads();   // h final

  // ---- global add pool: 8 chunks of 64 rows (tid<512) ----
  if (tid < 512) {
    int f = tid & 63, cch = tid >> 6;      // cch 0..7
    int rstart = cch * 64;
    float s = 0.f;
#pragma unroll 1
    for (int r = 0; r < 64; ++r) {
      unsigned u = hbf[(rstart + r)*SBF + f];
      union { unsigned u; float ff; } cv; cv.u = u << 16;
      s += cv.ff;
    }
    lds[POOLP + cch*64 + f] = s;
  }
  __syncthreads();
  if (tid < 64) {
    float pool = 0.f;
#pragma unroll
    for (int cc = 0; cc < 8; ++cc) pool += lds[POOLP + cc*64 + tid];
    lds[POOLED + tid] = pool;
  }
  __syncthreads();

  // ---- head MLP (fp32) ----
  if (tid < 256) {
    float acc = P.bh1[tid];
#pragma unroll 4
    for (int k = 0; k < 64; ++k) acc = fmaf(lds[POOLED+k], P.Wh1[k*256 + tid], acc);
    lds[Y1OFF + tid] = acc >= 0.f ? acc : 0.2f*acc;
  }
  __syncthreads();
  if (tid < 256) {
    float acc = P.bh2[tid];
#pragma unroll 4
    for (int k = 0; k < 256; ++k) acc = fmaf(lds[Y1OFF+k], P.Wh2[k*256 + tid], acc);
    lds[Y2OFF + tid] = acc >= 0.f ? acc : 0.2f*acc;
  }
  __syncthreads();
  if (tid < 64) {
    float acc = P.bh3[tid];
#pragma unroll 4
    for (int k = 0; k < 256; ++k) acc = fmaf(lds[Y2OFF+k], P.Wh3[k*64 + tid], acc);
    lds[Y3OFF + tid] = acc >= 0.f ? acc : 0.2f*acc;
  }
  __syncthreads();
  if (tid == 0) {
    float acc = P.bh4[0];
#pragma unroll 4
    for (int k = 0; k < 64; ++k) acc = fmaf(lds[Y3OFF+k], P.Wh4[k], acc);
    P.out[g] = acc;
  }
}

extern "C" void kernel_launch(void* const* d_in, const int* in_sizes, int n_in,
                              void* d_out, int out_size, void* d_ws, size_t ws_size,
                              hipStream_t stream) {
  Params P;
  P.x   = (const float*)d_in[0];
  P.W1  = (const float*)d_in[1];  P.b1  = (const float*)d_in[2];  P.a1 = (const float*)d_in[3];
  P.W2  = (const float*)d_in[4];  P.b2  = (const float*)d_in[5];  P.a2 = (const float*)d_in[6];
  P.Wc0 = (const float*)d_in[7];  P.bc0 = (const float*)d_in[8];
  P.Wc1 = (const float*)d_in[9];  P.bc1 = (const float*)d_in[10];
  P.Wc2 = (const float*)d_in[11]; P.bc2 = (const float*)d_in[12];
  P.Wc3 = (const float*)d_in[13]; P.bc3 = (const float*)d_in[14];
  P.W3  = (const float*)d_in[15]; P.b3  = (const float*)d_in[16]; P.a3 = (const float*)d_in[17];
  P.W4  = (const float*)d_in[18]; P.b4  = (const float*)d_in[19]; P.a4 = (const float*)d_in[20];
  P.Wh1 = (const float*)d_in[21]; P.bh1 = (const float*)d_in[22];
  P.Wh2 = (const float*)d_in[23]; P.bh2 = (const float*)d_in[24];
  P.Wh3 = (const float*)d_in[25]; P.bh3 = (const float*)d_in[26];
  P.Wh4 = (const float*)d_in[27]; P.bh4 = (const float*)d_in[28];
  P.out = (float*)d_out;

  (void)hipFuncSetAttribute(reinterpret_cast<const void*>(fused_gnn),
                            hipFuncAttributeMaxDynamicSharedMemorySize, LDS_BYTES);

  fused_gnn<<<NGRAPH, NT, LDS_BYTES, stream>>>(P);
}